// Round 9
// baseline (63.585 us; speedup 1.0000x reference)
//
#include <hip/hip_runtime.h>

typedef _Float16 f16;
typedef _Float16 f16x2 __attribute__((ext_vector_type(2)));
typedef _Float16 f16x4 __attribute__((ext_vector_type(4)));
typedef _Float16 f16x8 __attribute__((ext_vector_type(8)));
typedef float f32x2 __attribute__((ext_vector_type(2)));
typedef float f32x4 __attribute__((ext_vector_type(4)));

#define MFMA16(A, B, C) __builtin_amdgcn_mfma_f32_16x16x32_f16((A), (B), (C), 0, 0, 0)

static __device__ __forceinline__ f16x2 cvt2(f32x2 v) {
    return __builtin_bit_cast(f16x2, __builtin_amdgcn_cvt_pkrtz(v.x, v.y));
}
static __device__ __forceinline__ f16x4 cvt4(f32x4 v) {
    f16x2 a = cvt2(f32x2{v[0], v[1]});
    f16x2 b = cvt2(f32x2{v[2], v[3]});
    return __builtin_shufflevector(a, b, 0, 1, 2, 3);
}
static __device__ __forceinline__ f16x8 cvt8(f32x4 a, f32x4 b) {
    f16x4 lo = cvt4(a), hi = cvt4(b);
    return __builtin_shufflevector(lo, hi, 0, 1, 2, 3, 4, 5, 6, 7);
}

// B=4, N=512, X_DIM=64, T_DIM=32, H=128
// Block: 256 threads (4 waves), tile 32 i x 64 j. Grid (8,16,4) = 512 blocks = 2/CU.
// Per chunk: 1 i-row x 64 j. Layer 1 split in two ht-halves with progressive cvt
// (acc1 128->64 regs) so peak live ~210 < 256: gives the scheduler ~40 regs of
// slack to hoist ds_reads / interleave cvt with MFMA (r8 was at the 256 wall and
// behaved fully serialized). Layer-2/3 remain ht-half split (acc2 = 64 regs).
// launch_bounds(256,1): (256,2)'s 128-reg cap caused HBM scratch spill (r1-3);
// spill tripwire = FETCH_SIZE >> 3 MB.

__global__ __launch_bounds__(256, 1)
void pairmlp_kernel(const float* __restrict__ x, const float* __restrict__ y,
                    const float* __restrict__ t, const float* __restrict__ W1,
                    const float* __restrict__ b1, const float* __restrict__ W2,
                    const float* __restrict__ b2, const float* __restrict__ W3,
                    const float* __restrict__ b3, float* __restrict__ out)
{
    const int N = 512, H = 128, XD = 64, TD = 32;

    __shared__ f16x8 W1a[1024];   // 16 KB: [ht*2+ks][g][c]: W1[32ks+8g+i][16ht+c]
    __shared__ f16x8 W2a[2048];   // 32 KB: [hpt*4+ks][g][c]: W2[32ks+16(i>=4)+4g+(i&3)][16hpt+c]
    __shared__ f16x8 xt[256];     //  4 KB: x tile [32][64] f16, octet = row*8 + d/8
    __shared__ f16x8 yt[512];     //  8 KB: y tile [64][64] f16, octet = row*8 + (q ^ (row&7))
    __shared__ float tbs[128];    // t @ W1[64:] + b1 (plain h order, f32)

    const int tid = threadIdx.x;
    const int b = blockIdx.z;
    const int ibase = blockIdx.y * 32;
    const int jbase = blockIdx.x * 64;

    // ---------------- staging ----------------
    for (int o = tid; o < 1024; o += 256) {
        int c = o & 15, g = (o >> 4) & 3, kh = o >> 6;   // kh = ht*2+ks
        int ks = kh & 1, ht = kh >> 1;
        int h = ht * 16 + c;
        f16x8 v;
#pragma unroll
        for (int i = 0; i < 8; ++i) {
            int d = 32 * ks + 8 * g + i;
            v[i] = (f16)W1[d * H + h];
        }
        W1a[o] = v;
    }
    for (int o = tid; o < 2048; o += 256) {
        int c = o & 15, g = (o >> 4) & 3, kh = o >> 6;   // kh = hpt*4+ks
        int ks = kh & 3, hpt = kh >> 2;
        int hp = hpt * 16 + c;
        f16x8 v;
#pragma unroll
        for (int i = 0; i < 8; ++i) {
            int h = 32 * ks + ((i >> 2) << 4) + 4 * g + (i & 3);
            v[i] = (f16)W2[h * H + hp];
        }
        W2a[o] = v;
    }
    if (tid < 128) {
        float s = b1[tid];
#pragma unroll 8
        for (int d = 0; d < TD; ++d)
            s += t[b * TD + d] * W1[(XD + d) * H + tid];
        tbs[tid] = s;
    }
    {
        int o = tid;                  // x tile: 256 octets
        int r = o >> 3, q = o & 7;
        const float* xp = x + ((size_t)(b * N + ibase + r)) * XD + q * 8;
        f16x8 v;
#pragma unroll
        for (int e = 0; e < 8; ++e) v[e] = (f16)xp[e];
        xt[o] = v;
    }
#pragma unroll
    for (int oo = 0; oo < 2; ++oo) {  // y tile: 512 octets
        int o = tid + oo * 256;
        int r = o >> 3, q = o & 7;
        const float* yp = y + ((size_t)(b * N + jbase + r)) * XD + q * 8;
        f16x8 u;
#pragma unroll
        for (int e = 0; e < 8; ++e) u[e] = (f16)yp[e];
        yt[r * 8 + (q ^ (r & 7))] = u;
    }
    __syncthreads();

    const int w = tid >> 6;
    const int l = tid & 63;
    const int c = l & 15;
    const int g = l >> 4;
    const float b3v = b3[0];

    // permanent per-lane bias/weight tables (f16, fragment order) ~48 regs
    f16x8 tbo[4];                   // [ks][i]: tb at h = 32ks+16(i>=4)+4g+(i&3)
#pragma unroll
    for (int ks = 0; ks < 4; ++ks) {
        f16x8 v;
#pragma unroll
        for (int i = 0; i < 8; ++i) {
            int h = 32 * ks + ((i >> 2) << 4) + 4 * g + (i & 3);
            v[i] = (f16)tbs[h];
        }
        tbo[ks] = v;
    }
    f16x4 b2h[8], w3h[8];           // [ht][r]: value at h' = 16ht+4g+r
#pragma unroll
    for (int ht = 0; ht < 8; ++ht) {
        f16x4 bv, wv;
#pragma unroll
        for (int r = 0; r < 4; ++r) {
            int h0 = 16 * ht + 4 * g + r;
            bv[r] = (f16)b2[h0];
            wv[r] = (f16)W3[h0];
        }
        b2h[ht] = bv;
        w3h[ht] = wv;
    }

    const f32x4 zc = f32x4{0.f, 0.f, 0.f, 0.f};
    const f16x8 z8 = f16x8{};
    const f16x4 z4 = f16x4{};

#pragma unroll 1
    for (int ci = 0; ci < 8; ++ci) {
        const int il = w * 8 + ci;

        // x octets for this i-row (broadcast reads)
        f16x8 xv0 = xt[il * 8 + g];        // ks=0: d = 8g + e
        f16x8 xv1 = xt[il * 8 + 4 + g];    // ks=1: d = 32 + 8g + e

        // ---- layer 1 in two ht-halves; each half cvt'd into bf2 immediately ----
        // bf2 ks-group kk covers h in [32kk,32kk+32) = ht tiles {2kk,2kk+1};
        // half lh covers ht {4lh..4lh+3} = kk {2lh, 2lh+1}.
        f16x8 bf2[4][4];
#pragma unroll
        for (int lh = 0; lh < 2; ++lh) {
            f32x4 acc1[4][4];
#pragma unroll
            for (int ks = 0; ks < 2; ++ks) {
                f16x8 df[4];
#pragma unroll
                for (int mt = 0; mt < 4; ++mt) {
                    int jl = 16 * mt + c;
                    f16x8 yv = yt[jl * 8 + ((4 * ks + g) ^ (c & 7))];
                    f16x8 dd = (ks ? xv1 : xv0) - yv;   // v_pk_sub_f16
                    df[mt] = dd * dd;                    // v_pk_mul_f16
                }
#pragma unroll
                for (int hh = 0; hh < 4; ++hh) {
                    int ht = lh * 4 + hh;
                    f16x8 a = W1a[(ht * 2 + ks) * 64 + g * 16 + c];
#pragma unroll
                    for (int mt = 0; mt < 4; ++mt) {
                        if (ks == 0) acc1[hh][mt] = MFMA16(a, df[mt], zc);
                        else         acc1[hh][mt] = MFMA16(a, df[mt], acc1[hh][mt]);
                    }
                }
            }
#pragma unroll
            for (int kk = 0; kk < 2; ++kk)
#pragma unroll
                for (int mt = 0; mt < 4; ++mt) {
                    f16x8 v = cvt8(acc1[2 * kk][mt], acc1[2 * kk + 1][mt]) + tbo[2 * lh + kk];
                    bf2[2 * lh + kk][mt] = __builtin_elementwise_max(v, z8);
                }
        }

        // ---- layers 2+3 in two ht-halves (acc2 only 64 regs live) ----
        float s0 = 0.f, s1 = 0.f, s2 = 0.f, s3 = 0.f;
#pragma unroll
        for (int half = 0; half < 2; ++half) {
            f32x4 acc2[4][4];
#pragma unroll
            for (int ks = 0; ks < 4; ++ks) {
#pragma unroll
                for (int hh = 0; hh < 4; ++hh) {
                    int ht = half * 4 + hh;
                    f16x8 a = W2a[(ht * 4 + ks) * 64 + g * 16 + c];
#pragma unroll
                    for (int mt = 0; mt < 4; ++mt) {
                        if (ks == 0) acc2[hh][mt] = MFMA16(a, bf2[0][mt], zc);
                        else         acc2[hh][mt] = MFMA16(a, bf2[ks][mt], acc2[hh][mt]);
                    }
                }
            }
            // layer 3 partials: e = relu(cvt(acc2)+b2), s += e . w3
#pragma unroll
            for (int hh = 0; hh < 4; ++hh) {
                int ht = half * 4 + hh;
                f16x2 wlo = __builtin_shufflevector(w3h[ht], w3h[ht], 0, 1);
                f16x2 whi = __builtin_shufflevector(w3h[ht], w3h[ht], 2, 3);
#pragma unroll
                for (int mt = 0; mt < 4; ++mt) {
                    f16x4 e = __builtin_elementwise_max(cvt4(acc2[hh][mt]) + b2h[ht], z4);
                    f16x2 elo = __builtin_shufflevector(e, e, 0, 1);
                    f16x2 ehi = __builtin_shufflevector(e, e, 2, 3);
                    float* sp = (mt == 0) ? &s0 : (mt == 1) ? &s1 : (mt == 2) ? &s2 : &s3;
                    *sp = __builtin_amdgcn_fdot2(elo, wlo, *sp, false);
                    *sp = __builtin_amdgcn_fdot2(ehi, whi, *sp, false);
                }
            }
        }

        // reduce across g (rows of the padded transpose) and store
        s0 += __shfl_xor(s0, 16); s0 += __shfl_xor(s0, 32);
        s1 += __shfl_xor(s1, 16); s1 += __shfl_xor(s1, 32);
        s2 += __shfl_xor(s2, 16); s2 += __shfl_xor(s2, 32);
        s3 += __shfl_xor(s3, 16); s3 += __shfl_xor(s3, 32);

        if (g == 0) {
            size_t base = ((size_t)(b * N + ibase + il)) * N + jbase;
            out[base + c]      = s0 + b3v;
            out[base + 16 + c] = s1 + b3v;
            out[base + 32 + c] = s2 + b3v;
            out[base + 48 + c] = s3 + b3v;
        }
    }
}

extern "C" void kernel_launch(void* const* d_in, const int* in_sizes, int n_in,
                              void* d_out, int out_size, void* d_ws, size_t ws_size,
                              hipStream_t stream) {
    const float* x  = (const float*)d_in[0];
    const float* y  = (const float*)d_in[1];
    const float* t  = (const float*)d_in[2];
    const float* W1 = (const float*)d_in[3];
    const float* b1 = (const float*)d_in[4];
    const float* W2 = (const float*)d_in[5];
    const float* b2 = (const float*)d_in[6];
    const float* W3 = (const float*)d_in[7];
    const float* b3 = (const float*)d_in[8];
    float* out = (float*)d_out;

    dim3 grid(8, 16, 4);   // (j-tiles of 64, i-tiles of 32, batch)
    dim3 block(256);
    pairmlp_kernel<<<grid, block, 0, stream>>>(x, y, t, W1, b1, W2, b2, W3, b3, out);
}